// Round 5
// baseline (155758.179 us; speedup 1.0000x reference)
//
#include <hip/hip_runtime.h>
#include <hip/hip_bf16.h>
#include <math.h>

#define B_  64
#define S_  256
#define D_  1024
#define H_  1024
#define E_  128
#define O_  512
#define IN_ 1152   // D + E
#define G4_ 4096   // 4*H
#define KU_ 1152   // E + H   (u = [emb(128) | h(1024)])
#define KW_ 144    // per-wave K chunk in gates (8 waves * 144 = 1152)

typedef float f32x16 __attribute__((ext_vector_type(16)));
typedef float f32x4  __attribute__((ext_vector_type(4)));

// ws layout (floats):
//   u_g : [4 bgrp][1152 k][16 b]   (emb rows 0..127, h rows 128..1151)
//   c_g : [1024 jj][64 b]
//   lp  : [64 b][64 jc][512 o]
//   bar : 64 floats reserved (unsigned barrier counter at [0])
//   xwb : [CH*64 rows][4096]

// ---------------- inline grid barrier ----------------
__device__ __forceinline__ void gridbar(unsigned* bar, unsigned target) {
  __syncthreads();
  if (threadIdx.x == 0) {
    __threadfence();   // release
    __hip_atomic_fetch_add(bar, 1u, __ATOMIC_RELAXED, __HIP_MEMORY_SCOPE_AGENT);
    while (__hip_atomic_load(bar, __ATOMIC_RELAXED, __HIP_MEMORY_SCOPE_AGENT) < target) {
      __builtin_amdgcn_s_sleep(2);
    }
    __threadfence();   // acquire
  }
  __syncthreads();
}

// ---------------- init ----------------
__global__ __launch_bounds__(256) void k_init(
    const float* __restrict__ init_tensor,
    float* __restrict__ u_g, float* __restrict__ c_g,
    unsigned* __restrict__ bar)
{
  if (blockIdx.x == 0 && threadIdx.x == 0) *bar = 0u;
  const int NU = 4 * KU_ * 16;   // 73728
  const int NC = H_ * B_;        // 65536
  for (int idx = blockIdx.x * 256 + threadIdx.x; idx < NU + NC; idx += gridDim.x * 256) {
    if (idx < NU) {
      int k = (idx >> 4) % KU_;
      u_g[idx] = (k < E_) ? init_tensor[k] : 0.f;
    } else {
      c_g[idx - NU] = 0.f;
    }
  }
}

// ---------------- precompute xwb ----------------
__global__ __launch_bounds__(256) void k_xw(
    const float* __restrict__ hidden,
    const float* __restrict__ w_ih,
    const float* __restrict__ b_ih,
    const float* __restrict__ b_hh,
    float* __restrict__ xwb, int t0, int rows)
{
  __shared__ float a_t[16][132];
  __shared__ float b_t[16][132];
  const int tid = threadIdx.x;
  const int tx = tid & 15, ty = tid >> 4;
  const int m_base = blockIdx.x * 128;
  const int n_base = blockIdx.y * 128;
  float acc[8][8];
#pragma unroll
  for (int i = 0; i < 8; ++i)
#pragma unroll
    for (int j = 0; j < 8; ++j) acc[i][j] = 0.f;

  for (int k0 = 0; k0 < D_; k0 += 16) {
#pragma unroll
    for (int l = 0; l < 2; ++l) {
      int s = tid + l * 256;
      int r = s >> 2, kq = (s & 3) << 2;
      int m = m_base + r;
      float4 v = make_float4(0.f, 0.f, 0.f, 0.f);
      if (m < rows) {
        int t = t0 + (m >> 6), b = m & 63;
        v = *(const float4*)(hidden + ((size_t)b * S_ + t) * D_ + k0 + kq);
      }
      a_t[kq + 0][r] = v.x; a_t[kq + 1][r] = v.y; a_t[kq + 2][r] = v.z; a_t[kq + 3][r] = v.w;
      int j = n_base + r;
      float4 w = *(const float4*)(w_ih + (size_t)j * IN_ + k0 + kq);
      b_t[kq + 0][r] = w.x; b_t[kq + 1][r] = w.y; b_t[kq + 2][r] = w.z; b_t[kq + 3][r] = w.w;
    }
    __syncthreads();
#pragma unroll
    for (int k = 0; k < 16; ++k) {
      float av[8], bv[8];
      *(float4*)&av[0] = *(const float4*)&a_t[k][ty * 4];
      *(float4*)&av[4] = *(const float4*)&a_t[k][64 + ty * 4];
      *(float4*)&bv[0] = *(const float4*)&b_t[k][tx * 4];
      *(float4*)&bv[4] = *(const float4*)&b_t[k][64 + tx * 4];
#pragma unroll
      for (int i = 0; i < 8; ++i)
#pragma unroll
        for (int j = 0; j < 8; ++j)
          acc[i][j] = fmaf(av[i], bv[j], acc[i][j]);
    }
    __syncthreads();
  }
  float bias[8];
#pragma unroll
  for (int cj = 0; cj < 8; ++cj) {
    int col = n_base + ((cj < 4) ? (tx * 4 + cj) : (64 + tx * 4 + cj - 4));
    bias[cj] = b_ih[col] + b_hh[col];
  }
#pragma unroll
  for (int ri = 0; ri < 8; ++ri) {
    int m = m_base + ((ri < 4) ? (ty * 4 + ri) : (64 + ty * 4 + ri - 4));
    if (m < rows) {
      float4 s0 = make_float4(acc[ri][0] + bias[0], acc[ri][1] + bias[1],
                              acc[ri][2] + bias[2], acc[ri][3] + bias[3]);
      float4 s1 = make_float4(acc[ri][4] + bias[4], acc[ri][5] + bias[5],
                              acc[ri][6] + bias[6], acc[ri][7] + bias[7]);
      *(float4*)(xwb + (size_t)m * G4_ + n_base + tx * 4) = s0;
      *(float4*)(xwb + (size_t)m * G4_ + n_base + 64 + tx * 4) = s1;
    }
  }
}

// -------- macro helpers: ALL vector element indices are macro literals --------
#define LW1(W,I,KB) { const int kg = kbase + (KB) + (I); \
  (W)[(I)] = (kg < E_) ? w_ih[(size_t)j * IN_ + D_ + kg] \
                       : w_hh[(size_t)j * H_ + (kg - E_)]; }
#define LW16(W,KB) LW1(W,0,KB) LW1(W,1,KB) LW1(W,2,KB) LW1(W,3,KB) \
                   LW1(W,4,KB) LW1(W,5,KB) LW1(W,6,KB) LW1(W,7,KB) \
                   LW1(W,8,KB) LW1(W,9,KB) LW1(W,10,KB) LW1(W,11,KB) \
                   LW1(W,12,KB) LW1(W,13,KB) LW1(W,14,KB) LW1(W,15,KB)

#define FK1(W,I,KB) { const f32x16 uu = *(const f32x16*)(up + ((KB) + (I)) * 16); \
  acc += (W)[(I)] * uu; }
#define FK16(W,KB) FK1(W,0,KB) FK1(W,1,KB) FK1(W,2,KB) FK1(W,3,KB) \
                   FK1(W,4,KB) FK1(W,5,KB) FK1(W,6,KB) FK1(W,7,KB) \
                   FK1(W,8,KB) FK1(W,9,KB) FK1(W,10,KB) FK1(W,11,KB) \
                   FK1(W,12,KB) FK1(W,13,KB) FK1(W,14,KB) FK1(W,15,KB)

#define FC1(I) { const f32x16 hh = *(const f32x16*)&h_lds[(I) * 16]; \
  acc2 += wo[(I)] * hh; }

#define STC1(I) lp[(((size_t)(bgrp * 16 + (I))) * 64 + jc) * O_ + tid] = acc2[(I)];

// ---------------- persistent stepper ----------------
// grid 256 = (jc 0..63)*4 + (bgrp 0..3); block 512 = 8 waves.
// lane: g = lane>>4 (gate), jjl = lane&15 -> j = g*1024 + jc*16 + jjl
// wave: K chunk [wave*144, +144) of u = [emb(128)|h(1024)]
// Weights live in named ext_vector SSA values (w0..w8) -> no alloca -> no scratch.
__global__ __launch_bounds__(512, 1) void k_steps(
    const float* __restrict__ w_ih, const float* __restrict__ w_hh,
    const float* __restrict__ w_out, const float* __restrict__ b_out,
    const float* __restrict__ emb_table, const int* __restrict__ seq_lens,
    const float* __restrict__ xwb,
    float* __restrict__ u_g, float* __restrict__ c_g, float* __restrict__ lp,
    float* __restrict__ out, unsigned* __restrict__ bar, unsigned bar_base,
    int t0, int nsteps)
{
  __shared__ __align__(64) float u_lds[KU_ * 16];   // 73728 B
  __shared__ __align__(64) float red[8 * 64 * 20];  // 40960 B
  __shared__ __align__(64) float h_lds[16 * 16];    // 1024 B

  const int bid  = blockIdx.x;
  const int jc   = bid >> 2;
  const int bgrp = bid & 3;
  const int tid  = threadIdx.x;
  const int wave = tid >> 6;
  const int lane = tid & 63;
  const int g    = lane >> 4;
  const int jjl  = lane & 15;
  const int j    = g * H_ + jc * 16 + jjl;
  const int kbase = wave * KW_;

  // persistent per-lane weights: 144 gate weights in 9 named f32x16 SSA values
  f32x16 w0, w1, w2, w3, w4, w5, w6, w7, w8;
  LW16(w0, 0)   LW16(w1, 16)  LW16(w2, 32)  LW16(w3, 48)
  LW16(w4, 64)  LW16(w5, 80)  LW16(w6, 96)  LW16(w7, 112)
  LW16(w8, 128)

  f32x16 wo;
  {
    const float* wop = w_out + (size_t)tid * H_ + jc * 16;
#define LWO1(I) wo[(I)] = wop[(I)];
    LWO1(0) LWO1(1) LWO1(2) LWO1(3) LWO1(4) LWO1(5) LWO1(6) LWO1(7)
    LWO1(8) LWO1(9) LWO1(10) LWO1(11) LWO1(12) LWO1(13) LWO1(14) LWO1(15)
  }

  float* u_my = u_g + (size_t)bgrp * KU_ * 16;

  unsigned tgt = bar_base + 256u;

  for (int tt = 0; tt < nsteps; ++tt) {
    const int t = t0 + tt;

    // ---- stage this bgrp's u slice -> LDS
    for (int i = tid; i < KU_ * 4; i += 512)
      *(float4*)&u_lds[i * 4] = *(const float4*)&u_my[i * 4];
    __syncthreads();

    // ---- phase A: gates partial over this wave's K chunk (u broadcast from LDS)
    f32x16 acc;
#define ZA1(I) acc[(I)] = 0.f;
    ZA1(0) ZA1(1) ZA1(2) ZA1(3) ZA1(4) ZA1(5) ZA1(6) ZA1(7)
    ZA1(8) ZA1(9) ZA1(10) ZA1(11) ZA1(12) ZA1(13) ZA1(14) ZA1(15)
    {
      const float* up = u_lds + wave * KW_ * 16;
      FK16(w0, 0)   FK16(w1, 16)  FK16(w2, 32)  FK16(w3, 48)
      FK16(w4, 64)  FK16(w5, 80)  FK16(w6, 96)  FK16(w7, 112)
      FK16(w8, 128)
    }
    {
      float* rp = &red[(wave * 64 + lane) * 20];
      *(float4*)&rp[0]  = make_float4(acc[0],  acc[1],  acc[2],  acc[3]);
      *(float4*)&rp[4]  = make_float4(acc[4],  acc[5],  acc[6],  acc[7]);
      *(float4*)&rp[8]  = make_float4(acc[8],  acc[9],  acc[10], acc[11]);
      *(float4*)&rp[12] = make_float4(acc[12], acc[13], acc[14], acc[15]);
    }
    __syncthreads();

    // ---- phase B: K-reduce + LSTM cell (threads 0..255)
    if (tid < 256) {
      const int jl = tid & 15, bb = tid >> 4;
      const int b = bgrp * 16 + bb;
      const int jjg = jc * 16 + jl;
      float gv[4];
#pragma unroll
      for (int gg = 0; gg < 4; ++gg) {
        float s = xwb[((size_t)tt * B_ + b) * G4_ + gg * H_ + jjg];
#pragma unroll
        for (int w = 0; w < 8; ++w)
          s += red[(w * 64 + gg * 16 + jl) * 20 + bb];
        gv[gg] = s;
      }
      float iv = 1.f / (1.f + expf(-gv[0]));
      float fv = 1.f / (1.f + expf(-gv[1]));
      float gg2 = tanhf(gv[2]);
      float ov = 1.f / (1.f + expf(-gv[3]));
      float cc = fv * c_g[(size_t)jjg * B_ + b] + iv * gg2;
      c_g[(size_t)jjg * B_ + b] = cc;
      float hv = ov * tanhf(cc);
      u_my[(size_t)(E_ + jjg) * 16 + bb] = hv;
      h_lds[jl * 16 + bb] = hv;
    }
    __syncthreads();

    // ---- phase C: logits partial; o = tid
    {
      f32x16 acc2;
#define ZB1(I) acc2[(I)] = 0.f;
      ZB1(0) ZB1(1) ZB1(2) ZB1(3) ZB1(4) ZB1(5) ZB1(6) ZB1(7)
      ZB1(8) ZB1(9) ZB1(10) ZB1(11) ZB1(12) ZB1(13) ZB1(14) ZB1(15)
      FC1(0) FC1(1) FC1(2) FC1(3) FC1(4) FC1(5) FC1(6) FC1(7)
      FC1(8) FC1(9) FC1(10) FC1(11) FC1(12) FC1(13) FC1(14) FC1(15)
      STC1(0) STC1(1) STC1(2) STC1(3) STC1(4) STC1(5) STC1(6) STC1(7)
      STC1(8) STC1(9) STC1(10) STC1(11) STC1(12) STC1(13) STC1(14) STC1(15)
    }
    gridbar(bar, tgt); tgt += 256u;

    // ---- phase D: blocks 0..63: reduce logits, store, argmax, emb feedback
    if (bid < B_) {
      const int b = bid;
      float v = b_out[tid];
      const float* lpb = lp + (size_t)b * 64 * O_;
#pragma unroll 8
      for (int q = 0; q < 64; ++q) v += lpb[(size_t)q * O_ + tid];
      int len = seq_lens[b];
      out[((size_t)b * S_ + t) * O_ + tid] = (t < len) ? v : 0.f;
      float* sv = red;
      int*   si = (int*)(red + 512);
      sv[tid] = v; si[tid] = tid;
      __syncthreads();
      for (int s = 256; s > 0; s >>= 1) {
        if (tid < s) {
          float ov2 = sv[tid + s]; int oi = si[tid + s];
          if (ov2 > sv[tid] || (ov2 == sv[tid] && oi < si[tid])) { sv[tid] = ov2; si[tid] = oi; }
        }
        __syncthreads();
      }
      int idx = si[0];
      if (tid < E_)
        u_g[(size_t)(b >> 4) * KU_ * 16 + (size_t)tid * 16 + (b & 15)] =
            emb_table[(size_t)idx * E_ + tid];
    }
    gridbar(bar, tgt); tgt += 256u;
  }
}

extern "C" void kernel_launch(void* const* d_in, const int* in_sizes, int n_in,
                              void* d_out, int out_size, void* d_ws, size_t ws_size,
                              hipStream_t stream) {
  const float* hidden      = (const float*)d_in[0];
  const float* init_tensor = (const float*)d_in[1];
  const float* emb_table   = (const float*)d_in[2];
  const float* w_ih        = (const float*)d_in[3];
  const float* w_hh        = (const float*)d_in[4];
  const float* b_ih        = (const float*)d_in[5];
  const float* b_hh        = (const float*)d_in[6];
  const float* w_out       = (const float*)d_in[7];
  const float* b_out       = (const float*)d_in[8];
  const int*   seq_lens    = (const int*)d_in[9];
  float* out = (float*)d_out;
  float* ws  = (float*)d_ws;

  const size_t U_OFF  = 0;
  const size_t C_OFF  = U_OFF + (size_t)4 * KU_ * 16;      // 73728
  const size_t LP_OFF = C_OFF + (size_t)H_ * B_;           // +65536
  const size_t BAR_OFF= LP_OFF + (size_t)B_ * 64 * O_;     // +2097152
  const size_t XW_OFF = BAR_OFF + 64;                      // (~8.9 MB fixed)

  long long avail = (long long)(ws_size / 4) - (long long)XW_OFF;
  long long chl = avail / ((long long)B_ * G4_);
  int CH = (int)(chl < 1 ? 1 : (chl > S_ ? S_ : chl));

  unsigned* bar = (unsigned*)(ws + BAR_OFF);

  k_init<<<dim3(544), dim3(256), 0, stream>>>(init_tensor, ws + U_OFF, ws + C_OFF, bar);

  unsigned bar_base = 0;
  for (int t0 = 0; t0 < S_; t0 += CH) {
    int ch = (S_ - t0 < CH) ? (S_ - t0) : CH;
    int rows = ch * B_;
    dim3 pg((rows + 127) / 128, G4_ / 128);
    k_xw<<<pg, dim3(256), 0, stream>>>(hidden, w_ih, b_ih, b_hh, ws + XW_OFF, t0, rows);

    const float* xwbp = ws + XW_OFF;
    float* u_p  = ws + U_OFF;
    float* c_p  = ws + C_OFF;
    float* lp_p = ws + LP_OFF;
    int t0v = t0, nst = ch;
    void* args[] = { (void*)&w_ih, (void*)&w_hh, (void*)&w_out, (void*)&b_out,
                     (void*)&emb_table, (void*)&seq_lens, (void*)&xwbp,
                     (void*)&u_p, (void*)&c_p, (void*)&lp_p, (void*)&out,
                     (void*)&bar, (void*)&bar_base, (void*)&t0v, (void*)&nst };
    hipLaunchCooperativeKernel((void*)k_steps, dim3(256), dim3(512), args, 0, stream);
    bar_base += (unsigned)(2 * ch) * 256u;
  }
}

// Round 6
// 24210.292 us; speedup vs baseline: 6.4336x; 6.4336x over previous
//
#include <hip/hip_runtime.h>
#include <hip/hip_bf16.h>
#include <math.h>

#define B_  64
#define S_  256
#define D_  1024
#define H_  1024
#define E_  128
#define O_  512
#define IN_ 1152   // D + E
#define G4_ 4096   // 4*H
#define KU_ 1152   // E + H   (u = [emb(128) | h(1024)])
#define KW_ 144    // per-wave K chunk in gates (8 waves * 144 = 1152)

// ws layout (floats):
//   u_g  : [64 b][1152 k]          (emb cols 0..127, h cols 128..1151)
//   c_g  : [1024 jj][64 b]
//   lp   : [64 b][64 jc][512 o]
//   bar  : 64 floats reserved (unsigned barrier counter at [0])
//   wcat : [4096 rows][1152 k]  row = jc*64 + g*16 + jjl  (block-contiguous)
//   xwb  : [CH*64 rows][4096]

// ---------------- inline grid barrier ----------------
__device__ __forceinline__ void gridbar(unsigned* bar, unsigned target) {
  __syncthreads();
  if (threadIdx.x == 0) {
    __threadfence();   // release
    __hip_atomic_fetch_add(bar, 1u, __ATOMIC_RELAXED, __HIP_MEMORY_SCOPE_AGENT);
    while (__hip_atomic_load(bar, __ATOMIC_RELAXED, __HIP_MEMORY_SCOPE_AGENT) < target) {
      __builtin_amdgcn_s_sleep(2);
    }
    __threadfence();   // acquire
  }
  __syncthreads();
}

// ---------------- init: u, c, bar, permuted concat weights ----------------
__global__ __launch_bounds__(256) void k_init(
    const float* __restrict__ init_tensor,
    const float* __restrict__ w_ih,
    const float* __restrict__ w_hh,
    float* __restrict__ u_g, float* __restrict__ c_g,
    float* __restrict__ wcat,
    unsigned* __restrict__ bar)
{
  if (blockIdx.x == 0 && threadIdx.x == 0) *bar = 0u;
  const int NU = B_ * KU_;          // 73728   u[b][k]
  const int NC = H_ * B_;           // 65536
  const int NW = G4_ * KU_;         // 4718592 wcat
  const int total = NU + NC + NW;
  for (int idx = blockIdx.x * 256 + threadIdx.x; idx < total; idx += gridDim.x * 256) {
    if (idx < NU) {
      int k = idx % KU_;
      u_g[idx] = (k < E_) ? init_tensor[k] : 0.f;
    } else if (idx < NU + NC) {
      c_g[idx - NU] = 0.f;
    } else {
      int i = idx - NU - NC;
      int row = i / KU_;            // jc*64 + g*16 + jjl
      int k   = i - row * KU_;
      int g   = (row >> 4) & 3;
      int jcv = row >> 6;
      int jjl = row & 15;
      int j   = g * H_ + jcv * 16 + jjl;
      wcat[i] = (k < E_) ? w_ih[(size_t)j * IN_ + D_ + k]
                         : w_hh[(size_t)j * H_ + (k - E_)];
    }
  }
}

// ---------------- precompute xwb[t,b][j] = x_t[b] @ w_ih[:, :1024]^T + (b_ih+b_hh) ----------------
__global__ __launch_bounds__(256) void k_xw(
    const float* __restrict__ hidden,
    const float* __restrict__ w_ih,
    const float* __restrict__ b_ih,
    const float* __restrict__ b_hh,
    float* __restrict__ xwb, int t0, int rows)
{
  __shared__ float a_t[16][132];
  __shared__ float b_t[16][132];
  const int tid = threadIdx.x;
  const int tx = tid & 15, ty = tid >> 4;
  const int m_base = blockIdx.x * 128;
  const int n_base = blockIdx.y * 128;
  float acc[8][8];
#pragma unroll
  for (int i = 0; i < 8; ++i)
#pragma unroll
    for (int j = 0; j < 8; ++j) acc[i][j] = 0.f;

  for (int k0 = 0; k0 < D_; k0 += 16) {
#pragma unroll
    for (int l = 0; l < 2; ++l) {
      int s = tid + l * 256;
      int r = s >> 2, kq = (s & 3) << 2;
      int m = m_base + r;
      float4 v = make_float4(0.f, 0.f, 0.f, 0.f);
      if (m < rows) {
        int t = t0 + (m >> 6), b = m & 63;
        v = *(const float4*)(hidden + ((size_t)b * S_ + t) * D_ + k0 + kq);
      }
      a_t[kq + 0][r] = v.x; a_t[kq + 1][r] = v.y; a_t[kq + 2][r] = v.z; a_t[kq + 3][r] = v.w;
      int j = n_base + r;
      float4 w = *(const float4*)(w_ih + (size_t)j * IN_ + k0 + kq);
      b_t[kq + 0][r] = w.x; b_t[kq + 1][r] = w.y; b_t[kq + 2][r] = w.z; b_t[kq + 3][r] = w.w;
    }
    __syncthreads();
#pragma unroll
    for (int k = 0; k < 16; ++k) {
      float av[8], bv[8];
      *(float4*)&av[0] = *(const float4*)&a_t[k][ty * 4];
      *(float4*)&av[4] = *(const float4*)&a_t[k][64 + ty * 4];
      *(float4*)&bv[0] = *(const float4*)&b_t[k][tx * 4];
      *(float4*)&bv[4] = *(const float4*)&b_t[k][64 + tx * 4];
#pragma unroll
      for (int i = 0; i < 8; ++i)
#pragma unroll
        for (int j = 0; j < 8; ++j)
          acc[i][j] = fmaf(av[i], bv[j], acc[i][j]);
    }
    __syncthreads();
  }
  float bias[8];
#pragma unroll
  for (int cj = 0; cj < 8; ++cj) {
    int col = n_base + ((cj < 4) ? (tx * 4 + cj) : (64 + tx * 4 + cj - 4));
    bias[cj] = b_ih[col] + b_hh[col];
  }
#pragma unroll
  for (int ri = 0; ri < 8; ++ri) {
    int m = m_base + ((ri < 4) ? (ty * 4 + ri) : (64 + ty * 4 + ri - 4));
    if (m < rows) {
      float4 s0 = make_float4(acc[ri][0] + bias[0], acc[ri][1] + bias[1],
                              acc[ri][2] + bias[2], acc[ri][3] + bias[3]);
      float4 s1 = make_float4(acc[ri][4] + bias[4], acc[ri][5] + bias[5],
                              acc[ri][6] + bias[6], acc[ri][7] + bias[7]);
      *(float4*)(xwb + (size_t)m * G4_ + n_base + tx * 4) = s0;
      *(float4*)(xwb + (size_t)m * G4_ + n_base + 64 + tx * 4) = s1;
    }
  }
}

// 4 gates x 4 batches x 4 k per inner iter, all names static
#define FMA4(G,Q) \
  acc##G##Q = fmaf(wv##G.x, uv##Q.x, acc##G##Q); \
  acc##G##Q = fmaf(wv##G.y, uv##Q.y, acc##G##Q); \
  acc##G##Q = fmaf(wv##G.z, uv##Q.z, acc##G##Q); \
  acc##G##Q = fmaf(wv##G.w, uv##Q.w, acc##G##Q);

#define STR(G,Q) red[(wave * 64 + (G) * 16 + jg) * 20 + bg * 4 + (Q)] = acc##G##Q;

// phase C: k-step macro, all static
#define FCK(KK, WK) { const float wk = (WK); \
  const float4 h0 = *(const float4*)&h_lds[(KK) * 16 + 0]; \
  const float4 h1 = *(const float4*)&h_lds[(KK) * 16 + 4]; \
  const float4 h2 = *(const float4*)&h_lds[(KK) * 16 + 8]; \
  const float4 h3 = *(const float4*)&h_lds[(KK) * 16 + 12]; \
  a20.x = fmaf(wk, h0.x, a20.x); a20.y = fmaf(wk, h0.y, a20.y); \
  a20.z = fmaf(wk, h0.z, a20.z); a20.w = fmaf(wk, h0.w, a20.w); \
  a21.x = fmaf(wk, h1.x, a21.x); a21.y = fmaf(wk, h1.y, a21.y); \
  a21.z = fmaf(wk, h1.z, a21.z); a21.w = fmaf(wk, h1.w, a21.w); \
  a22.x = fmaf(wk, h2.x, a22.x); a22.y = fmaf(wk, h2.y, a22.y); \
  a22.z = fmaf(wk, h2.z, a22.z); a22.w = fmaf(wk, h2.w, a22.w); \
  a23.x = fmaf(wk, h3.x, a23.x); a23.y = fmaf(wk, h3.y, a23.y); \
  a23.z = fmaf(wk, h3.z, a23.z); a23.w = fmaf(wk, h3.w, a23.w); }

#define STB(BB, VAL) lp[(((size_t)(bgrp * 16 + (BB))) * 64 + jc) * O_ + tid] = (VAL);

// ---------------- persistent stepper (streamed weights, ~70 VGPR) ----------------
// grid 256 = (jc 0..63)*4 + (bgrp 0..3); block 512 = 8 waves.
// wave: K chunk [wave*144, +144). lane: jg = lane&15, bg = lane>>4.
// lane tile: 4 gates (rows g*16+jg of block's wcat slice) x 4 batches (bg*4+q).
__global__ __launch_bounds__(512, 1) void k_steps(
    const float* __restrict__ wcat,
    const float* __restrict__ w_out, const float* __restrict__ b_out,
    const float* __restrict__ emb_table, const int* __restrict__ seq_lens,
    const float* __restrict__ xwb,
    float* __restrict__ u_g, float* __restrict__ c_g, float* __restrict__ lp,
    float* __restrict__ out, unsigned* __restrict__ bar, unsigned bar_base,
    int t0, int nsteps)
{
  __shared__ __align__(64) float u_lds[16 * KU_];   // [b][k] 73728 B
  __shared__ __align__(64) float red[8 * 64 * 20];  // 40960 B
  __shared__ __align__(64) float h_lds[16 * 16];    // 1024 B

  const int bid  = blockIdx.x;
  const int jc   = bid >> 2;
  const int bgrp = bid & 3;
  const int tid  = threadIdx.x;
  const int wave = tid >> 6;
  const int lane = tid & 63;
  const int jg   = lane & 15;
  const int bg   = lane >> 4;
  const int kbase = wave * KW_;

  // weight row pointers for this lane's 4 gate-rows (block slice is contiguous)
  const float* wp0 = wcat + (size_t)(jc * 64 +  0 + jg) * KU_ + kbase;
  const float* wp1 = wcat + (size_t)(jc * 64 + 16 + jg) * KU_ + kbase;
  const float* wp2 = wcat + (size_t)(jc * 64 + 32 + jg) * KU_ + kbase;
  const float* wp3 = wcat + (size_t)(jc * 64 + 48 + jg) * KU_ + kbase;

  // logits weights (16 floats) in 4 named float4
  float4 woq0, woq1, woq2, woq3;
  {
    const float* wop = w_out + (size_t)tid * H_ + jc * 16;
    woq0 = *(const float4*)(wop + 0);
    woq1 = *(const float4*)(wop + 4);
    woq2 = *(const float4*)(wop + 8);
    woq3 = *(const float4*)(wop + 12);
  }

  float* u_my = u_g + (size_t)bgrp * 16 * KU_;   // [16 b][1152 k]

  unsigned tgt = bar_base + 256u;

  for (int tt = 0; tt < nsteps; ++tt) {
    const int t = t0 + tt;

    // ---- stage this bgrp's u slice -> LDS ([b][k], straight copy)
    for (int i = tid; i < 16 * KU_ / 4; i += 512)
      *(float4*)&u_lds[i * 4] = *(const float4*)&u_my[i * 4];
    __syncthreads();

    // ---- phase A: 4g x 4b tile over this wave's K chunk; w streams from global
    {
      float acc00 = 0.f, acc01 = 0.f, acc02 = 0.f, acc03 = 0.f;
      float acc10 = 0.f, acc11 = 0.f, acc12 = 0.f, acc13 = 0.f;
      float acc20 = 0.f, acc21 = 0.f, acc22 = 0.f, acc23 = 0.f;
      float acc30 = 0.f, acc31 = 0.f, acc32 = 0.f, acc33 = 0.f;
      const float* up0 = u_lds + (bg * 4 + 0) * KU_ + kbase;
      const float* up1 = u_lds + (bg * 4 + 1) * KU_ + kbase;
      const float* up2 = u_lds + (bg * 4 + 2) * KU_ + kbase;
      const float* up3 = u_lds + (bg * 4 + 3) * KU_ + kbase;
#pragma unroll 2
      for (int kq = 0; kq < KW_; kq += 4) {
        const float4 wv0 = *(const float4*)(wp0 + kq);
        const float4 wv1 = *(const float4*)(wp1 + kq);
        const float4 wv2 = *(const float4*)(wp2 + kq);
        const float4 wv3 = *(const float4*)(wp3 + kq);
        const float4 uv0 = *(const float4*)(up0 + kq);
        const float4 uv1 = *(const float4*)(up1 + kq);
        const float4 uv2 = *(const float4*)(up2 + kq);
        const float4 uv3 = *(const float4*)(up3 + kq);
        FMA4(0,0) FMA4(0,1) FMA4(0,2) FMA4(0,3)
        FMA4(1,0) FMA4(1,1) FMA4(1,2) FMA4(1,3)
        FMA4(2,0) FMA4(2,1) FMA4(2,2) FMA4(2,3)
        FMA4(3,0) FMA4(3,1) FMA4(3,2) FMA4(3,3)
      }
      STR(0,0) STR(0,1) STR(0,2) STR(0,3)
      STR(1,0) STR(1,1) STR(1,2) STR(1,3)
      STR(2,0) STR(2,1) STR(2,2) STR(2,3)
      STR(3,0) STR(3,1) STR(3,2) STR(3,3)
    }
    __syncthreads();

    // ---- phase B: K-reduce + LSTM cell (threads 0..255), block-local
    if (tid < 256) {
      const int jl = tid & 15, bb = tid >> 4;
      const int b = bgrp * 16 + bb;
      const int jjg = jc * 16 + jl;
      float gv[4];
#pragma unroll
      for (int gg = 0; gg < 4; ++gg) {
        float s = xwb[((size_t)tt * B_ + b) * G4_ + gg * H_ + jjg];
#pragma unroll
        for (int w = 0; w < 8; ++w)
          s += red[(w * 64 + gg * 16 + jl) * 20 + bb];
        gv[gg] = s;
      }
      float iv = 1.f / (1.f + expf(-gv[0]));
      float fv = 1.f / (1.f + expf(-gv[1]));
      float gg2 = tanhf(gv[2]);
      float ov = 1.f / (1.f + expf(-gv[3]));
      float cc = fv * c_g[(size_t)jjg * B_ + b] + iv * gg2;
      c_g[(size_t)jjg * B_ + b] = cc;
      float hv = ov * tanhf(cc);
      u_my[(size_t)bb * KU_ + E_ + jjg] = hv;
      h_lds[jl * 16 + bb] = hv;
    }
    __syncthreads();

    // ---- phase C: logits partial over this block's 16-k h slice; o = tid
    {
      float4 a20 = make_float4(0.f, 0.f, 0.f, 0.f);
      float4 a21 = make_float4(0.f, 0.f, 0.f, 0.f);
      float4 a22 = make_float4(0.f, 0.f, 0.f, 0.f);
      float4 a23 = make_float4(0.f, 0.f, 0.f, 0.f);
      FCK(0,  woq0.x) FCK(1,  woq0.y) FCK(2,  woq0.z) FCK(3,  woq0.w)
      FCK(4,  woq1.x) FCK(5,  woq1.y) FCK(6,  woq1.z) FCK(7,  woq1.w)
      FCK(8,  woq2.x) FCK(9,  woq2.y) FCK(10, woq2.z) FCK(11, woq2.w)
      FCK(12, woq3.x) FCK(13, woq3.y) FCK(14, woq3.z) FCK(15, woq3.w)
      STB(0,  a20.x) STB(1,  a20.y) STB(2,  a20.z) STB(3,  a20.w)
      STB(4,  a21.x) STB(5,  a21.y) STB(6,  a21.z) STB(7,  a21.w)
      STB(8,  a22.x) STB(9,  a22.y) STB(10, a22.z) STB(11, a22.w)
      STB(12, a23.x) STB(13, a23.y) STB(14, a23.z) STB(15, a23.w)
    }
    gridbar(bar, tgt); tgt += 256u;

    // ---- phase D: blocks 0..63 (b = bid): reduce logits, store, argmax, emb feedback
    if (bid < B_) {
      const int b = bid;
      float v = b_out[tid];
      const float* lpb = lp + (size_t)b * 64 * O_;
#pragma unroll 8
      for (int q = 0; q < 64; ++q) v += lpb[(size_t)q * O_ + tid];
      int len = seq_lens[b];
      out[((size_t)b * S_ + t) * O_ + tid] = (t < len) ? v : 0.f;
      float* sv = red;
      int*   si = (int*)(red + 512);
      sv[tid] = v; si[tid] = tid;
      __syncthreads();
      for (int s = 256; s > 0; s >>= 1) {
        if (tid < s) {
          float ov2 = sv[tid + s]; int oi = si[tid + s];
          if (ov2 > sv[tid] || (ov2 == sv[tid] && oi < si[tid])) { sv[tid] = ov2; si[tid] = oi; }
        }
        __syncthreads();
      }
      int idx = si[0];
      if (tid < E_)
        u_g[((size_t)(b >> 4) * 16 + (b & 15)) * KU_ + tid] =
            emb_table[(size_t)idx * E_ + tid];
    }
    gridbar(bar, tgt); tgt += 256u;
  }
}

extern "C" void kernel_launch(void* const* d_in, const int* in_sizes, int n_in,
                              void* d_out, int out_size, void* d_ws, size_t ws_size,
                              hipStream_t stream) {
  const float* hidden      = (const float*)d_in[0];
  const float* init_tensor = (const float*)d_in[1];
  const float* emb_table   = (const float*)d_in[2];
  const float* w_ih        = (const float*)d_in[3];
  const float* w_hh        = (const float*)d_in[4];
  const float* b_ih        = (const float*)d_in[5];
  const float* b_hh        = (const float*)d_in[6];
  const float* w_out       = (const float*)d_in[7];
  const float* b_out       = (const float*)d_in[8];
  const int*   seq_lens    = (const int*)d_in[9];
  float* out = (float*)d_out;
  float* ws  = (float*)d_ws;

  const size_t U_OFF   = 0;
  const size_t C_OFF   = U_OFF + (size_t)B_ * KU_;         // 73728
  const size_t LP_OFF  = C_OFF + (size_t)H_ * B_;          // +65536
  const size_t BAR_OFF = LP_OFF + (size_t)B_ * 64 * O_;    // +2097152
  const size_t WC_OFF  = BAR_OFF + 64;
  const size_t XW_OFF  = WC_OFF + (size_t)G4_ * KU_;       // +4718592 (~27.8 MB fixed)

  long long avail = (long long)(ws_size / 4) - (long long)XW_OFF;
  long long chl = avail / ((long long)B_ * G4_);
  int CH = (int)(chl < 1 ? 1 : (chl > S_ ? S_ : chl));

  unsigned* bar = (unsigned*)(ws + BAR_OFF);

  k_init<<<dim3(2048), dim3(256), 0, stream>>>(init_tensor, w_ih, w_hh,
                                               ws + U_OFF, ws + C_OFF,
                                               ws + WC_OFF, bar);

  unsigned bar_base = 0;
  for (int t0 = 0; t0 < S_; t0 += CH) {
    int ch = (S_ - t0 < CH) ? (S_ - t0) : CH;
    int rows = ch * B_;
    dim3 pg((rows + 127) / 128, G4_ / 128);
    k_xw<<<pg, dim3(256), 0, stream>>>(hidden, w_ih, b_ih, b_hh, ws + XW_OFF, t0, rows);

    const float* wcatp = ws + WC_OFF;
    const float* xwbp  = ws + XW_OFF;
    float* u_p  = ws + U_OFF;
    float* c_p  = ws + C_OFF;
    float* lp_p = ws + LP_OFF;
    int t0v = t0, nst = ch;
    void* args[] = { (void*)&wcatp, (void*)&w_out, (void*)&b_out,
                     (void*)&emb_table, (void*)&seq_lens, (void*)&xwbp,
                     (void*)&u_p, (void*)&c_p, (void*)&lp_p, (void*)&out,
                     (void*)&bar, (void*)&bar_base, (void*)&t0v, (void*)&nst };
    hipLaunchCooperativeKernel((void*)k_steps, dim3(256), dim3(512), args, 0, stream);
    bar_base += (unsigned)(2 * ch) * 256u;
  }
}

// Round 7
// 22400.102 us; speedup vs baseline: 6.9535x; 1.0808x over previous
//
#include <hip/hip_runtime.h>
#include <hip/hip_bf16.h>
#include <math.h>

#define B_  64
#define S_  256
#define D_  1024
#define H_  1024
#define E_  128
#define O_  512
#define IN_ 1152   // D + E
#define G4_ 4096   // 4*H
#define KU_ 1152   // E + H   (u = [emb(128) | h(1024)])
#define KW_ 144    // per-wave K chunk in gates (8 waves * 144 = 1152)

// ws layout (floats):
//   u_g  : [2 par][4 bgrp][1152 k][16 b]  (parity = global step t&1; emb rows 0..127)
//   c_g  : [1024 jj][64 b]
//   lp   : [64 b][64 jc][512 o]
//   bar  : 64 (unsigned counter at [0])
//   pamv : [64 b][4 oq]  partial argmax value
//   pami : [64 b][4 oq]  partial argmax index (int)
//   wcat : [4096 rows][1152 k]   row = jc*64 + g*16 + jjl
//   xwb  : [CH*64 rows][4096]

// ---------------- inline grid barrier ----------------
__device__ __forceinline__ void gridbar(unsigned* bar, unsigned target) {
  __syncthreads();
  if (threadIdx.x == 0) {
    __threadfence();   // release (L2 writeback, agent scope)
    __hip_atomic_fetch_add(bar, 1u, __ATOMIC_RELAXED, __HIP_MEMORY_SCOPE_AGENT);
    while (__hip_atomic_load(bar, __ATOMIC_RELAXED, __HIP_MEMORY_SCOPE_AGENT) < target) {
      __builtin_amdgcn_s_sleep(2);
    }
    __threadfence();   // acquire (L2 invalidate)
  }
  __syncthreads();
}

// ---------------- init: u slice0, c, bar, permuted concat weights ----------------
__global__ __launch_bounds__(256) void k_init(
    const float* __restrict__ init_tensor,
    const float* __restrict__ w_ih,
    const float* __restrict__ w_hh,
    float* __restrict__ u_g, float* __restrict__ c_g,
    float* __restrict__ wcat,
    unsigned* __restrict__ bar)
{
  if (blockIdx.x == 0 && threadIdx.x == 0) *bar = 0u;
  const int NU = 4 * KU_ * 16;      // 73728  (parity-0 slice only)
  const int NC = H_ * B_;           // 65536
  const int NW = G4_ * KU_;         // 4718592
  const int total = NU + NC + NW;
  for (int idx = blockIdx.x * 256 + threadIdx.x; idx < total; idx += gridDim.x * 256) {
    if (idx < NU) {
      int k = (idx >> 4) % KU_;
      u_g[idx] = (k < E_) ? init_tensor[k] : 0.f;
    } else if (idx < NU + NC) {
      c_g[idx - NU] = 0.f;
    } else {
      int i = idx - NU - NC;
      int row = i / KU_;            // jc*64 + g*16 + jjl
      int k   = i - row * KU_;
      int g   = (row >> 4) & 3;
      int jcv = row >> 6;
      int jjl = row & 15;
      int j   = g * H_ + jcv * 16 + jjl;
      wcat[i] = (k < E_) ? w_ih[(size_t)j * IN_ + D_ + k]
                         : w_hh[(size_t)j * H_ + (k - E_)];
    }
  }
}

// ---------------- precompute xwb[t,b][j] = x_t[b] @ w_ih[:, :1024]^T + (b_ih+b_hh) ----------------
__global__ __launch_bounds__(256) void k_xw(
    const float* __restrict__ hidden,
    const float* __restrict__ w_ih,
    const float* __restrict__ b_ih,
    const float* __restrict__ b_hh,
    float* __restrict__ xwb, int t0, int rows)
{
  __shared__ float a_t[16][132];
  __shared__ float b_t[16][132];
  const int tid = threadIdx.x;
  const int tx = tid & 15, ty = tid >> 4;
  const int m_base = blockIdx.x * 128;
  const int n_base = blockIdx.y * 128;
  float acc[8][8];
#pragma unroll
  for (int i = 0; i < 8; ++i)
#pragma unroll
    for (int j = 0; j < 8; ++j) acc[i][j] = 0.f;

  for (int k0 = 0; k0 < D_; k0 += 16) {
#pragma unroll
    for (int l = 0; l < 2; ++l) {
      int s = tid + l * 256;
      int r = s >> 2, kq = (s & 3) << 2;
      int m = m_base + r;
      float4 v = make_float4(0.f, 0.f, 0.f, 0.f);
      if (m < rows) {
        int t = t0 + (m >> 6), b = m & 63;
        v = *(const float4*)(hidden + ((size_t)b * S_ + t) * D_ + k0 + kq);
      }
      a_t[kq + 0][r] = v.x; a_t[kq + 1][r] = v.y; a_t[kq + 2][r] = v.z; a_t[kq + 3][r] = v.w;
      int j = n_base + r;
      float4 w = *(const float4*)(w_ih + (size_t)j * IN_ + k0 + kq);
      b_t[kq + 0][r] = w.x; b_t[kq + 1][r] = w.y; b_t[kq + 2][r] = w.z; b_t[kq + 3][r] = w.w;
    }
    __syncthreads();
#pragma unroll
    for (int k = 0; k < 16; ++k) {
      float av[8], bv[8];
      *(float4*)&av[0] = *(const float4*)&a_t[k][ty * 4];
      *(float4*)&av[4] = *(const float4*)&a_t[k][64 + ty * 4];
      *(float4*)&bv[0] = *(const float4*)&b_t[k][tx * 4];
      *(float4*)&bv[4] = *(const float4*)&b_t[k][64 + tx * 4];
#pragma unroll
      for (int i = 0; i < 8; ++i)
#pragma unroll
        for (int j = 0; j < 8; ++j)
          acc[i][j] = fmaf(av[i], bv[j], acc[i][j]);
    }
    __syncthreads();
  }
  float bias[8];
#pragma unroll
  for (int cj = 0; cj < 8; ++cj) {
    int col = n_base + ((cj < 4) ? (tx * 4 + cj) : (64 + tx * 4 + cj - 4));
    bias[cj] = b_ih[col] + b_hh[col];
  }
#pragma unroll
  for (int ri = 0; ri < 8; ++ri) {
    int m = m_base + ((ri < 4) ? (ty * 4 + ri) : (64 + ty * 4 + ri - 4));
    if (m < rows) {
      float4 s0 = make_float4(acc[ri][0] + bias[0], acc[ri][1] + bias[1],
                              acc[ri][2] + bias[2], acc[ri][3] + bias[3]);
      float4 s1 = make_float4(acc[ri][4] + bias[4], acc[ri][5] + bias[5],
                              acc[ri][6] + bias[6], acc[ri][7] + bias[7]);
      *(float4*)(xwb + (size_t)m * G4_ + n_base + tx * 4) = s0;
      *(float4*)(xwb + (size_t)m * G4_ + n_base + 64 + tx * 4) = s1;
    }
  }
}

// phase A: per gate G, 4 k-components x 4 batches (k ascending per accumulator,
// bit-identical to previous rounds)
#define FMA_G(G) \
  acc##G##0=fmaf(wv##G.x, uv0.x, acc##G##0); acc##G##1=fmaf(wv##G.x, uv0.y, acc##G##1); \
  acc##G##2=fmaf(wv##G.x, uv0.z, acc##G##2); acc##G##3=fmaf(wv##G.x, uv0.w, acc##G##3); \
  acc##G##0=fmaf(wv##G.y, uv1.x, acc##G##0); acc##G##1=fmaf(wv##G.y, uv1.y, acc##G##1); \
  acc##G##2=fmaf(wv##G.y, uv1.z, acc##G##2); acc##G##3=fmaf(wv##G.y, uv1.w, acc##G##3); \
  acc##G##0=fmaf(wv##G.z, uv2.x, acc##G##0); acc##G##1=fmaf(wv##G.z, uv2.y, acc##G##1); \
  acc##G##2=fmaf(wv##G.z, uv2.z, acc##G##2); acc##G##3=fmaf(wv##G.z, uv2.w, acc##G##3); \
  acc##G##0=fmaf(wv##G.w, uv3.x, acc##G##0); acc##G##1=fmaf(wv##G.w, uv3.y, acc##G##1); \
  acc##G##2=fmaf(wv##G.w, uv3.z, acc##G##2); acc##G##3=fmaf(wv##G.w, uv3.w, acc##G##3);

#define STR(G,Q) red[(wave * 64 + (G) * 16 + jg) * 20 + bg * 4 + (Q)] = acc##G##Q;

// phase C k-step (unchanged)
#define FCK(KK, WK) { const float wk = (WK); \
  const float4 h0 = *(const float4*)&h_lds[(KK) * 16 + 0]; \
  const float4 h1 = *(const float4*)&h_lds[(KK) * 16 + 4]; \
  const float4 h2 = *(const float4*)&h_lds[(KK) * 16 + 8]; \
  const float4 h3 = *(const float4*)&h_lds[(KK) * 16 + 12]; \
  a20.x = fmaf(wk, h0.x, a20.x); a20.y = fmaf(wk, h0.y, a20.y); \
  a20.z = fmaf(wk, h0.z, a20.z); a20.w = fmaf(wk, h0.w, a20.w); \
  a21.x = fmaf(wk, h1.x, a21.x); a21.y = fmaf(wk, h1.y, a21.y); \
  a21.z = fmaf(wk, h1.z, a21.z); a21.w = fmaf(wk, h1.w, a21.w); \
  a22.x = fmaf(wk, h2.x, a22.x); a22.y = fmaf(wk, h2.y, a22.y); \
  a22.z = fmaf(wk, h2.z, a22.z); a22.w = fmaf(wk, h2.w, a22.w); \
  a23.x = fmaf(wk, h3.x, a23.x); a23.y = fmaf(wk, h3.y, a23.y); \
  a23.z = fmaf(wk, h3.z, a23.z); a23.w = fmaf(wk, h3.w, a23.w); }

#define STB(BB, VAL) lp[(((size_t)(bgrp * 16 + (BB))) * 64 + jc) * O_ + tid] = (VAL);

// ---------------- persistent stepper ----------------
// grid 256 = (jc)*4 + bgrp; block 512 = 8 waves.
// u_lds [k][16b]; u_g parity-double-buffered on global step t&1.
__global__ __launch_bounds__(512, 1) void k_steps(
    const float* __restrict__ wcat,
    const float* __restrict__ w_out, const float* __restrict__ b_out,
    const float* __restrict__ emb_table, const int* __restrict__ seq_lens,
    const float* __restrict__ xwb,
    float* __restrict__ u_g, float* __restrict__ c_g, float* __restrict__ lp,
    float* __restrict__ pamv, int* __restrict__ pami,
    float* __restrict__ out, unsigned* __restrict__ bar, unsigned bar_base,
    int t0, int nsteps, int use_pamx)
{
  __shared__ __align__(64) float u_lds[KU_ * 16];   // [k][16b] 73728 B
  __shared__ __align__(64) float red[8 * 64 * 20];  // 40960 B
  __shared__ __align__(64) float h_lds[16 * 16];
  __shared__ int   s_idx[16];
  __shared__ float sv[128];
  __shared__ int   si[128];

  const int bid  = blockIdx.x;
  const int jc   = bid >> 2;
  const int bgrp = bid & 3;
  const int tid  = threadIdx.x;
  const int wave = tid >> 6;
  const int lane = tid & 63;
  const int jg   = lane & 15;
  const int bg   = lane >> 4;
  const int kbase = wave * KW_;

  const float* wp0 = wcat + (size_t)(jc * 64 +  0 + jg) * KU_ + kbase;
  const float* wp1 = wcat + (size_t)(jc * 64 + 16 + jg) * KU_ + kbase;
  const float* wp2 = wcat + (size_t)(jc * 64 + 32 + jg) * KU_ + kbase;
  const float* wp3 = wcat + (size_t)(jc * 64 + 48 + jg) * KU_ + kbase;

  float4 woq0, woq1, woq2, woq3;
  {
    const float* wop = w_out + (size_t)tid * H_ + jc * 16;
    woq0 = *(const float4*)(wop + 0);
    woq1 = *(const float4*)(wop + 4);
    woq2 = *(const float4*)(wop + 8);
    woq3 = *(const float4*)(wop + 12);
  }

  unsigned tgt = bar_base + 256u;

  for (int tt = 0; tt < nsteps; ++tt) {
    const int t = t0 + tt;
    // parity-double-buffered u slices (read t&1, write (t+1)&1)
    const float* u_rd = u_g + ((size_t)((t & 1) * 4 + bgrp)) * KU_ * 16;
    float*       u_wr = u_g + ((size_t)(((t + 1) & 1) * 4 + bgrp)) * KU_ * 16;

    // ---- stage u -> LDS [k][16b]
    if (tt == 0 && !use_pamx) {
      // first step of first launch: emb+h both from k_init-filled slice 0
      for (int i = tid; i < KU_ * 4; i += 512)
        *(float4*)&u_lds[i * 4] = *(const float4*)&u_rd[i * 4];
      __syncthreads();
    } else {
      // finish argmax for this bgrp's 16 batches (first-index across oq asc)
      if (tid < 16) {
        int b = bgrp * 16 + tid;
        float bv = pamv[b * 4 + 0]; int bi = pami[b * 4 + 0];
#pragma unroll
        for (int oq = 1; oq < 4; ++oq) {
          float v2 = pamv[b * 4 + oq]; int i2 = pami[b * 4 + oq];
          if (v2 > bv) { bv = v2; bi = i2; }
        }
        s_idx[tid] = bi;
      }
      // h rows (k=128..1151) from global parity slice
      for (int i = tid; i < 4096; i += 512)
        *(float4*)&u_lds[E_ * 16 + i * 4] = *(const float4*)&u_rd[E_ * 16 + i * 4];
      __syncthreads();
      // emb rows (k=0..127) gathered straight into LDS
      {
        int bb = tid & 15, kq = (tid >> 4) << 2;   // kq 0..124
        float4 e = *(const float4*)(emb_table + (size_t)s_idx[bb] * E_ + kq);
        u_lds[(kq + 0) * 16 + bb] = e.x;
        u_lds[(kq + 1) * 16 + bb] = e.y;
        u_lds[(kq + 2) * 16 + bb] = e.z;
        u_lds[(kq + 3) * 16 + bb] = e.w;
      }
      __syncthreads();
    }

    // ---- phase A: 4g x 4b tile; w streams (global), u broadcast (LDS, conflict-free)
    {
      float acc00 = 0.f, acc01 = 0.f, acc02 = 0.f, acc03 = 0.f;
      float acc10 = 0.f, acc11 = 0.f, acc12 = 0.f, acc13 = 0.f;
      float acc20 = 0.f, acc21 = 0.f, acc22 = 0.f, acc23 = 0.f;
      float acc30 = 0.f, acc31 = 0.f, acc32 = 0.f, acc33 = 0.f;
      const float* up = u_lds + kbase * 16 + bg * 4;
#pragma unroll 2
      for (int kq = 0; kq < KW_; kq += 4) {
        const float4 wv0 = *(const float4*)(wp0 + kq);
        const float4 wv1 = *(const float4*)(wp1 + kq);
        const float4 wv2 = *(const float4*)(wp2 + kq);
        const float4 wv3 = *(const float4*)(wp3 + kq);
        const float4 uv0 = *(const float4*)(up + (kq + 0) * 16);
        const float4 uv1 = *(const float4*)(up + (kq + 1) * 16);
        const float4 uv2 = *(const float4*)(up + (kq + 2) * 16);
        const float4 uv3 = *(const float4*)(up + (kq + 3) * 16);
        FMA_G(0) FMA_G(1) FMA_G(2) FMA_G(3)
      }
      STR(0,0) STR(0,1) STR(0,2) STR(0,3)
      STR(1,0) STR(1,1) STR(1,2) STR(1,3)
      STR(2,0) STR(2,1) STR(2,2) STR(2,3)
      STR(3,0) STR(3,1) STR(3,2) STR(3,3)
    }
    __syncthreads();

    // ---- phase B: K-reduce + LSTM cell (threads 0..255)
    if (tid < 256) {
      const int jl = tid & 15, bb = tid >> 4;
      const int b = bgrp * 16 + bb;
      const int jjg = jc * 16 + jl;
      float gv[4];
#pragma unroll
      for (int gg = 0; gg < 4; ++gg) {
        float s = xwb[((size_t)tt * B_ + b) * G4_ + gg * H_ + jjg];
#pragma unroll
        for (int w = 0; w < 8; ++w)
          s += red[(w * 64 + gg * 16 + jl) * 20 + bb];
        gv[gg] = s;
      }
      float iv = 1.f / (1.f + expf(-gv[0]));
      float fv = 1.f / (1.f + expf(-gv[1]));
      float gg2 = tanhf(gv[2]);
      float ov = 1.f / (1.f + expf(-gv[3]));
      float cc = fv * c_g[(size_t)jjg * B_ + b] + iv * gg2;
      c_g[(size_t)jjg * B_ + b] = cc;
      float hv = ov * tanhf(cc);
      u_wr[(size_t)(E_ + jjg) * 16 + bb] = hv;   // next-parity slice
      h_lds[jl * 16 + bb] = hv;
    }
    __syncthreads();

    // ---- phase C: logits partial over this block's 16-k h slice; o = tid
    {
      float4 a20 = make_float4(0.f, 0.f, 0.f, 0.f);
      float4 a21 = make_float4(0.f, 0.f, 0.f, 0.f);
      float4 a22 = make_float4(0.f, 0.f, 0.f, 0.f);
      float4 a23 = make_float4(0.f, 0.f, 0.f, 0.f);
      FCK(0,  woq0.x) FCK(1,  woq0.y) FCK(2,  woq0.z) FCK(3,  woq0.w)
      FCK(4,  woq1.x) FCK(5,  woq1.y) FCK(6,  woq1.z) FCK(7,  woq1.w)
      FCK(8,  woq2.x) FCK(9,  woq2.y) FCK(10, woq2.z) FCK(11, woq2.w)
      FCK(12, woq3.x) FCK(13, woq3.y) FCK(14, woq3.z) FCK(15, woq3.w)
      STB(0,  a20.x) STB(1,  a20.y) STB(2,  a20.z) STB(3,  a20.w)
      STB(4,  a21.x) STB(5,  a21.y) STB(6,  a21.z) STB(7,  a21.w)
      STB(8,  a22.x) STB(9,  a22.y) STB(10, a22.z) STB(11, a22.w)
      STB(12, a23.x) STB(13, a23.y) STB(14, a23.z) STB(15, a23.w)
    }
    gridbar(bar, tgt); tgt += 256u;

    // ---- phase D (ALL 256 blocks): b = bid>>2, 128-o slice oq = bid&3.
    // Exact same summation order as before: v = b_out[o]; jc 0..63 ascending.
    {
      const int b = bid >> 2, oq = bid & 3, obase = oq * 128;
      if (tid < 128) {
        float v = b_out[obase + tid];
        const float* lpb = lp + ((size_t)b * 64) * O_ + obase + tid;
#pragma unroll 8
        for (int q = 0; q < 64; ++q) v += lpb[(size_t)q * O_];
        int len = seq_lens[b];
        out[((size_t)b * S_ + t) * O_ + obase + tid] = (t < len) ? v : 0.f;
        sv[tid] = v; si[tid] = obase + tid;
      }
      __syncthreads();
      for (int s = 64; s > 0; s >>= 1) {
        if (tid < s) {
          float ov2 = sv[tid + s]; int oi = si[tid + s];
          if (ov2 > sv[tid] || (ov2 == sv[tid] && oi < si[tid])) { sv[tid] = ov2; si[tid] = oi; }
        }
        __syncthreads();
      }
      if (tid == 0) { pamv[b * 4 + oq] = sv[0]; pami[b * 4 + oq] = si[0]; }
    }
    gridbar(bar, tgt); tgt += 256u;
  }
}

extern "C" void kernel_launch(void* const* d_in, const int* in_sizes, int n_in,
                              void* d_out, int out_size, void* d_ws, size_t ws_size,
                              hipStream_t stream) {
  const float* hidden      = (const float*)d_in[0];
  const float* init_tensor = (const float*)d_in[1];
  const float* emb_table   = (const float*)d_in[2];
  const float* w_ih        = (const float*)d_in[3];
  const float* w_hh        = (const float*)d_in[4];
  const float* b_ih        = (const float*)d_in[5];
  const float* b_hh        = (const float*)d_in[6];
  const float* w_out       = (const float*)d_in[7];
  const float* b_out       = (const float*)d_in[8];
  const int*   seq_lens    = (const int*)d_in[9];
  float* out = (float*)d_out;
  float* ws  = (float*)d_ws;

  const size_t U_OFF   = 0;                                 // 2*4*1152*16 = 147456
  const size_t C_OFF   = U_OFF + (size_t)2 * 4 * KU_ * 16;
  const size_t LP_OFF  = C_OFF + (size_t)H_ * B_;           // +65536
  const size_t BAR_OFF = LP_OFF + (size_t)B_ * 64 * O_;     // +2097152
  const size_t PAMV_OFF= BAR_OFF + 64;
  const size_t PAMI_OFF= PAMV_OFF + 256;
  const size_t WC_OFF  = PAMI_OFF + 256;
  const size_t XW_OFF  = WC_OFF + (size_t)G4_ * KU_;        // +4718592 (~28.3 MB fixed)

  long long avail = (long long)(ws_size / 4) - (long long)XW_OFF;
  long long chl = avail / ((long long)B_ * G4_);
  int CH = (int)(chl < 1 ? 1 : (chl > S_ ? S_ : chl));

  unsigned* bar = (unsigned*)(ws + BAR_OFF);

  k_init<<<dim3(2048), dim3(256), 0, stream>>>(init_tensor, w_ih, w_hh,
                                               ws + U_OFF, ws + C_OFF,
                                               ws + WC_OFF, bar);

  unsigned bar_base = 0;
  for (int t0 = 0; t0 < S_; t0 += CH) {
    int ch = (S_ - t0 < CH) ? (S_ - t0) : CH;
    int rows = ch * B_;
    dim3 pg((rows + 127) / 128, G4_ / 128);
    k_xw<<<pg, dim3(256), 0, stream>>>(hidden, w_ih, b_ih, b_hh, ws + XW_OFF, t0, rows);

    const float* wcatp = ws + WC_OFF;
    const float* xwbp  = ws + XW_OFF;
    float* u_p  = ws + U_OFF;
    float* c_p  = ws + C_OFF;
    float* lp_p = ws + LP_OFF;
    float* pv_p = ws + PAMV_OFF;
    int*   pi_p = (int*)(ws + PAMI_OFF);
    int t0v = t0, nst = ch, upx = (t0 > 0) ? 1 : 0;
    void* args[] = { (void*)&wcatp, (void*)&w_out, (void*)&b_out,
                     (void*)&emb_table, (void*)&seq_lens, (void*)&xwbp,
                     (void*)&u_p, (void*)&c_p, (void*)&lp_p,
                     (void*)&pv_p, (void*)&pi_p, (void*)&out,
                     (void*)&bar, (void*)&bar_base, (void*)&t0v, (void*)&nst, (void*)&upx };
    hipLaunchCooperativeKernel((void*)k_steps, dim3(256), dim3(512), args, 0, stream);
    bar_base += (unsigned)(2 * ch) * 256u;
  }
}

// Round 8
// 19678.502 us; speedup vs baseline: 7.9151x; 1.1383x over previous
//
#include <hip/hip_runtime.h>
#include <hip/hip_bf16.h>
#include <math.h>

#define B_  64
#define S_  256
#define D_  1024
#define H_  1024
#define E_  128
#define O_  512
#define IN_ 1152   // D + E
#define G4_ 4096   // 4*H
#define KU_ 1152   // E + H   (u = [emb(128) | h(1024)])

// ws layout (floats):
//   u_g   : [2 par][4 bgrp][1152 k][16 b]
//   c_g   : [1024 jj][64 b]
//   lp    : [64 b][64 jc][512 o]
//   bar   : 64 (unsigned counter at [0])
//   pamv/pami : [64 b][4 oq]
//   wcat3 : [64 jc][288 kunit][64 rows][4 k]   row = g*16 + jg
//   xwb   : [CH*64 rows][4096]

__device__ __forceinline__ void gldlds16(const float* g, float* l) {
  __builtin_amdgcn_global_load_lds((const __attribute__((address_space(1))) void*)g,
                                   (__attribute__((address_space(3))) void*)l, 16, 0, 0);
}
__device__ __forceinline__ void gldlds4(const float* g, float* l) {
  __builtin_amdgcn_global_load_lds((const __attribute__((address_space(1))) void*)g,
                                   (__attribute__((address_space(3))) void*)l, 4, 0, 0);
}

// ---------------- inline grid barrier ----------------
// NOTE: __syncthreads makes each wave drain its own vmcnt before s_barrier, so
// tid0's fences correctly cover all block writes.
__device__ __forceinline__ void gridbar(unsigned* bar, unsigned target) {
  __syncthreads();
  if (threadIdx.x == 0) {
    __threadfence();   // release
    __hip_atomic_fetch_add(bar, 1u, __ATOMIC_RELAXED, __HIP_MEMORY_SCOPE_AGENT);
    while (__hip_atomic_load(bar, __ATOMIC_RELAXED, __HIP_MEMORY_SCOPE_AGENT) < target) {
      __builtin_amdgcn_s_sleep(2);
    }
    __threadfence();   // acquire
  }
  __syncthreads();
}

// ---------------- init: u parity-0, c, bar, wcat3 ----------------
__global__ __launch_bounds__(256) void k_init(
    const float* __restrict__ init_tensor,
    const float* __restrict__ w_ih,
    const float* __restrict__ w_hh,
    float* __restrict__ u_g, float* __restrict__ c_g,
    float* __restrict__ wcat3,
    unsigned* __restrict__ bar)
{
  if (blockIdx.x == 0 && threadIdx.x == 0) *bar = 0u;
  const int NU = 4 * KU_ * 16;      // 73728  (parity-0 slice)
  const int NC = H_ * B_;           // 65536
  const int NW = G4_ * KU_;         // 4718592
  const int total = NU + NC + NW;
  for (int idx = blockIdx.x * 256 + threadIdx.x; idx < total; idx += gridDim.x * 256) {
    if (idx < NU) {
      int k = (idx >> 4) % KU_;
      u_g[idx] = (k < E_) ? init_tensor[k] : 0.f;
    } else if (idx < NU + NC) {
      c_g[idx - NU] = 0.f;
    } else {
      int i = idx - NU - NC;
      int uidx = i >> 8;            // jc*288 + kunit
      int r    = (i >> 2) & 63;     // row = g*16 + jg
      int kk   = i & 3;
      int jc   = uidx / 288;
      int kun  = uidx - jc * 288;
      int g    = r >> 4;
      int jg   = r & 15;
      int j    = g * H_ + jc * 16 + jg;
      int k    = kun * 4 + kk;
      wcat3[i] = (k < E_) ? w_ih[(size_t)j * IN_ + D_ + k]
                          : w_hh[(size_t)j * H_ + (k - E_)];
    }
  }
}

// ---------------- precompute xwb ----------------
__global__ __launch_bounds__(256) void k_xw(
    const float* __restrict__ hidden,
    const float* __restrict__ w_ih,
    const float* __restrict__ b_ih,
    const float* __restrict__ b_hh,
    float* __restrict__ xwb, int t0, int rows)
{
  __shared__ float a_t[16][132];
  __shared__ float b_t[16][132];
  const int tid = threadIdx.x;
  const int tx = tid & 15, ty = tid >> 4;
  const int m_base = blockIdx.x * 128;
  const int n_base = blockIdx.y * 128;
  float acc[8][8];
#pragma unroll
  for (int i = 0; i < 8; ++i)
#pragma unroll
    for (int j = 0; j < 8; ++j) acc[i][j] = 0.f;

  for (int k0 = 0; k0 < D_; k0 += 16) {
#pragma unroll
    for (int l = 0; l < 2; ++l) {
      int s = tid + l * 256;
      int r = s >> 2, kq = (s & 3) << 2;
      int m = m_base + r;
      float4 v = make_float4(0.f, 0.f, 0.f, 0.f);
      if (m < rows) {
        int t = t0 + (m >> 6), b = m & 63;
        v = *(const float4*)(hidden + ((size_t)b * S_ + t) * D_ + k0 + kq);
      }
      a_t[kq + 0][r] = v.x; a_t[kq + 1][r] = v.y; a_t[kq + 2][r] = v.z; a_t[kq + 3][r] = v.w;
      int j = n_base + r;
      float4 w = *(const float4*)(w_ih + (size_t)j * IN_ + k0 + kq);
      b_t[kq + 0][r] = w.x; b_t[kq + 1][r] = w.y; b_t[kq + 2][r] = w.z; b_t[kq + 3][r] = w.w;
    }
    __syncthreads();
#pragma unroll
    for (int k = 0; k < 16; ++k) {
      float av[8], bv[8];
      *(float4*)&av[0] = *(const float4*)&a_t[k][ty * 4];
      *(float4*)&av[4] = *(const float4*)&a_t[k][64 + ty * 4];
      *(float4*)&bv[0] = *(const float4*)&b_t[k][tx * 4];
      *(float4*)&bv[4] = *(const float4*)&b_t[k][64 + tx * 4];
#pragma unroll
      for (int i = 0; i < 8; ++i)
#pragma unroll
        for (int j = 0; j < 8; ++j)
          acc[i][j] = fmaf(av[i], bv[j], acc[i][j]);
    }
    __syncthreads();
  }
  float bias[8];
#pragma unroll
  for (int cj = 0; cj < 8; ++cj) {
    int col = n_base + ((cj < 4) ? (tx * 4 + cj) : (64 + tx * 4 + cj - 4));
    bias[cj] = b_ih[col] + b_hh[col];
  }
#pragma unroll
  for (int ri = 0; ri < 8; ++ri) {
    int m = m_base + ((ri < 4) ? (ty * 4 + ri) : (64 + ty * 4 + ri - 4));
    if (m < rows) {
      float4 s0 = make_float4(acc[ri][0] + bias[0], acc[ri][1] + bias[1],
                              acc[ri][2] + bias[2], acc[ri][3] + bias[3]);
      float4 s1 = make_float4(acc[ri][4] + bias[4], acc[ri][5] + bias[5],
                              acc[ri][6] + bias[6], acc[ri][7] + bias[7]);
      *(float4*)(xwb + (size_t)m * G4_ + n_base + tx * 4) = s0;
      *(float4*)(xwb + (size_t)m * G4_ + n_base + 64 + tx * 4) = s1;
    }
  }
}

// phase A FMA order (bit-identical to R7: k ascending per accumulator)
#define FMA_G(G) \
  acc##G##0=fmaf(wv##G.x, uv0.x, acc##G##0); acc##G##1=fmaf(wv##G.x, uv0.y, acc##G##1); \
  acc##G##2=fmaf(wv##G.x, uv0.z, acc##G##2); acc##G##3=fmaf(wv##G.x, uv0.w, acc##G##3); \
  acc##G##0=fmaf(wv##G.y, uv1.x, acc##G##0); acc##G##1=fmaf(wv##G.y, uv1.y, acc##G##1); \
  acc##G##2=fmaf(wv##G.y, uv1.z, acc##G##2); acc##G##3=fmaf(wv##G.y, uv1.w, acc##G##3); \
  acc##G##0=fmaf(wv##G.z, uv2.x, acc##G##0); acc##G##1=fmaf(wv##G.z, uv2.y, acc##G##1); \
  acc##G##2=fmaf(wv##G.z, uv2.z, acc##G##2); acc##G##3=fmaf(wv##G.z, uv2.w, acc##G##3); \
  acc##G##0=fmaf(wv##G.w, uv3.x, acc##G##0); acc##G##1=fmaf(wv##G.w, uv3.y, acc##G##1); \
  acc##G##2=fmaf(wv##G.w, uv3.z, acc##G##2); acc##G##3=fmaf(wv##G.w, uv3.w, acc##G##3);

#define STR(G,Q) red[(wave * 64 + (G) * 16 + jg) * 20 + bg * 4 + (Q)] = acc##G##Q;

#define FCK(KK, WK) { const float wk = (WK); \
  const float4 h0 = *(const float4*)&h_lds[(KK) * 16 + 0]; \
  const float4 h1 = *(const float4*)&h_lds[(KK) * 16 + 4]; \
  const float4 h2 = *(const float4*)&h_lds[(KK) * 16 + 8]; \
  const float4 h3 = *(const float4*)&h_lds[(KK) * 16 + 12]; \
  a20.x = fmaf(wk, h0.x, a20.x); a20.y = fmaf(wk, h0.y, a20.y); \
  a20.z = fmaf(wk, h0.z, a20.z); a20.w = fmaf(wk, h0.w, a20.w); \
  a21.x = fmaf(wk, h1.x, a21.x); a21.y = fmaf(wk, h1.y, a21.y); \
  a21.z = fmaf(wk, h1.z, a21.z); a21.w = fmaf(wk, h1.w, a21.w); \
  a22.x = fmaf(wk, h2.x, a22.x); a22.y = fmaf(wk, h2.y, a22.y); \
  a22.z = fmaf(wk, h2.z, a22.z); a22.w = fmaf(wk, h2.w, a22.w); \
  a23.x = fmaf(wk, h3.x, a23.x); a23.y = fmaf(wk, h3.y, a23.y); \
  a23.z = fmaf(wk, h3.z, a23.z); a23.w = fmaf(wk, h3.w, a23.w); }

#define STB(BB, VAL) lp[(((size_t)(bgrp * 16 + (BB))) * 64 + jc) * O_ + tid] = (VAL);

// ---------------- persistent stepper: async-pipelined phase A ----------------
// grid 256 = jc*4 + bgrp; block 512 = 8 waves; wave k-chunk = [wave*144, +144)
// = 36 units of 4k. Per unit: 1 gld_lds dwordx4 (w) + 1 gld_lds dword (u),
// ring depth 4, steady-state s_waitcnt vmcnt(6).
__global__ __launch_bounds__(512, 1) void k_steps(
    const float* __restrict__ wcat3,
    const float* __restrict__ w_out, const float* __restrict__ b_out,
    const float* __restrict__ emb_table, const int* __restrict__ seq_lens,
    const float* __restrict__ xwb,
    float* __restrict__ u_g, float* __restrict__ c_g, float* __restrict__ lp,
    float* __restrict__ pamv, int* __restrict__ pami,
    float* __restrict__ out, unsigned* __restrict__ bar, unsigned bar_base,
    int t0, int nsteps, int use_pamx)
{
  __shared__ __align__(64) float w_ring[8][4][256];  // 32 KB
  __shared__ __align__(64) float u_ring[8][4][64];   //  8 KB
  __shared__ __align__(64) float red[8 * 64 * 20];   // 40 KB
  __shared__ __align__(64) float h_lds[16 * 16];
  __shared__ int   s_idx[16];
  __shared__ float sv[128];
  __shared__ int   si[128];

  const int bid  = blockIdx.x;
  const int jc   = bid >> 2;
  const int bgrp = bid & 3;
  const int tid  = threadIdx.x;
  const int wave = tid >> 6;
  const int lane = tid & 63;
  const int jg   = lane & 15;
  const int bg   = lane >> 4;
  const int kbu  = wave * 36;   // unit base of this wave's k-chunk

  float4 woq0, woq1, woq2, woq3;
  {
    const float* wop = w_out + (size_t)tid * H_ + jc * 16;
    woq0 = *(const float4*)(wop + 0);
    woq1 = *(const float4*)(wop + 4);
    woq2 = *(const float4*)(wop + 8);
    woq3 = *(const float4*)(wop + 12);
  }

  float* wr = &w_ring[wave][0][0];
  float* ur = &u_ring[wave][0][0];

  unsigned tgt = bar_base + 256u;

  for (int tt = 0; tt < nsteps; ++tt) {
    const int t = t0 + tt;
    const float* u_rd = u_g + ((size_t)((t & 1) * 4 + bgrp)) * KU_ * 16;
    float*       u_wr = u_g + ((size_t)(((t + 1) & 1) * 4 + bgrp)) * KU_ * 16;
    const bool from_pam = (use_pamx != 0) || (tt > 0);

    const float* embL = emb_table;   // valid per-lane base set below when from_pam
    if (from_pam) {
      if (tid < 16) {
        int b = bgrp * 16 + tid;
        float bv = pamv[b * 4 + 0]; int bi = pami[b * 4 + 0];
#pragma unroll
        for (int oq = 1; oq < 4; ++oq) {
          float v2 = pamv[b * 4 + oq]; int i2 = pami[b * 4 + oq];
          if (v2 > bv) { bv = v2; bi = i2; }
        }
        s_idx[tid] = bi;
      }
      __syncthreads();
      embL = emb_table + (size_t)s_idx[jg] * E_ + bg;   // + k later (kqg*4)
    }

#define A_ISSUE(KQ) do { \
      const int slot_ = (KQ) & 3; \
      const int kqg_  = kbu + (KQ); \
      gldlds16(wcat3 + (((size_t)(jc * 288 + kqg_)) << 8) + (lane << 2), wr + slot_ * 256); \
      const float* us_ = (from_pam && kqg_ < 32) ? (embL + kqg_ * 4) \
                                                 : (u_rd + kqg_ * 64 + lane); \
      gldlds4(us_, ur + slot_ * 64); \
    } while (0)

    // ---- phase A
    float acc00 = 0.f, acc01 = 0.f, acc02 = 0.f, acc03 = 0.f;
    float acc10 = 0.f, acc11 = 0.f, acc12 = 0.f, acc13 = 0.f;
    float acc20 = 0.f, acc21 = 0.f, acc22 = 0.f, acc23 = 0.f;
    float acc30 = 0.f, acc31 = 0.f, acc32 = 0.f, acc33 = 0.f;

    A_ISSUE(0); A_ISSUE(1); A_ISSUE(2);
    for (int kq = 0; kq < 36; ++kq) {
      if (kq < 33) {
        A_ISSUE(kq + 3);
        asm volatile("s_waitcnt vmcnt(6)" ::: "memory");
      } else if (kq == 33) {
        asm volatile("s_waitcnt vmcnt(4)" ::: "memory");
      } else if (kq == 34) {
        asm volatile("s_waitcnt vmcnt(2)" ::: "memory");
      } else {
        asm volatile("s_waitcnt vmcnt(0)" ::: "memory");
      }
      {
        const int slot_ = kq & 3;
        const float* wp_ = wr + slot_ * 256;
        const float* up_ = ur + slot_ * 64;
        const float4 wv0 = *(const float4*)(wp_ + jg * 4);
        const float4 wv1 = *(const float4*)(wp_ + (16 + jg) * 4);
        const float4 wv2 = *(const float4*)(wp_ + (32 + jg) * 4);
        const float4 wv3 = *(const float4*)(wp_ + (48 + jg) * 4);
        const float4 uv0 = *(const float4*)(up_ + bg * 4);
        const float4 uv1 = *(const float4*)(up_ + 16 + bg * 4);
        const float4 uv2 = *(const float4*)(up_ + 32 + bg * 4);
        const float4 uv3 = *(const float4*)(up_ + 48 + bg * 4);
        FMA_G(0) FMA_G(1) FMA_G(2) FMA_G(3)
      }
    }
#undef A_ISSUE

    STR(0,0) STR(0,1) STR(0,2) STR(0,3)
    STR(1,0) STR(1,1) STR(1,2) STR(1,3)
    STR(2,0) STR(2,1) STR(2,2) STR(2,3)
    STR(3,0) STR(3,1) STR(3,2) STR(3,3)
    __syncthreads();

    // ---- phase B: K-reduce + LSTM cell (threads 0..255)
    if (tid < 256) {
      const int jl = tid & 15, bb = tid >> 4;
      const int b = bgrp * 16 + bb;
      const int jjg = jc * 16 + jl;
      float gv[4];
#pragma unroll
      for (int gg = 0; gg < 4; ++gg) {
        float s = xwb[((size_t)tt * B_ + b) * G4_ + gg * H_ + jjg];
#pragma unroll
        for (int w = 0; w < 8; ++w)
          s += red[(w * 64 + gg * 16 + jl) * 20 + bb];
        gv[gg] = s;
      }
      float iv = 1.f / (1.f + expf(-gv[0]));
      float fv = 1.f / (1.f + expf(-gv[1]));
      float gg2 = tanhf(gv[2]);
      float ov = 1.f / (1.f + expf(-gv[3]));
      float cc = fv * c_g[(size_t)jjg * B_ + b] + iv * gg2;
      c_g[(size_t)jjg * B_ + b] = cc;
      float hv = ov * tanhf(cc);
      u_wr[(size_t)(E_ + jjg) * 16 + bb] = hv;
      h_lds[jl * 16 + bb] = hv;
    }
    __syncthreads();

    // ---- phase C: logits partial; o = tid
    {
      float4 a20 = make_float4(0.f, 0.f, 0.f, 0.f);
      float4 a21 = make_float4(0.f, 0.f, 0.f, 0.f);
      float4 a22 = make_float4(0.f, 0.f, 0.f, 0.f);
      float4 a23 = make_float4(0.f, 0.f, 0.f, 0.f);
      FCK(0,  woq0.x) FCK(1,  woq0.y) FCK(2,  woq0.z) FCK(3,  woq0.w)
      FCK(4,  woq1.x) FCK(5,  woq1.y) FCK(6,  woq1.z) FCK(7,  woq1.w)
      FCK(8,  woq2.x) FCK(9,  woq2.y) FCK(10, woq2.z) FCK(11, woq2.w)
      FCK(12, woq3.x) FCK(13, woq3.y) FCK(14, woq3.z) FCK(15, woq3.w)
      STB(0,  a20.x) STB(1,  a20.y) STB(2,  a20.z) STB(3,  a20.w)
      STB(4,  a21.x) STB(5,  a21.y) STB(6,  a21.z) STB(7,  a21.w)
      STB(8,  a22.x) STB(9,  a22.y) STB(10, a22.z) STB(11, a22.w)
      STB(12, a23.x) STB(13, a23.y) STB(14, a23.z) STB(15, a23.w)
    }
    gridbar(bar, tgt); tgt += 256u;

    // ---- phase D (ALL 256 blocks): b = bid>>2, oq = bid&3 (128-o slice)
    {
      const int b = bid >> 2, oq = bid & 3, obase = oq * 128;
      if (tid < 128) {
        float v = b_out[obase + tid];
        const float* lpb = lp + ((size_t)b * 64) * O_ + obase + tid;
#pragma unroll 8
        for (int q = 0; q < 64; ++q) v += lpb[(size_t)q * O_];
        int len = seq_lens[b];
        out[((size_t)b * S_ + t) * O_ + obase + tid] = (t < len) ? v : 0.f;
        sv[tid] = v; si[tid] = obase + tid;
      }
      __syncthreads();
      for (int s = 64; s > 0; s >>= 1) {
        if (tid < s) {
          float ov2 = sv[tid + s]; int oi = si[tid + s];
          if (ov2 > sv[tid] || (ov2 == sv[tid] && oi < si[tid])) { sv[tid] = ov2; si[tid] = oi; }
        }
        __syncthreads();
      }
      if (tid == 0) { pamv[b * 4 + oq] = sv[0]; pami[b * 4 + oq] = si[0]; }
    }
    gridbar(bar, tgt); tgt += 256u;
  }
}

extern "C" void kernel_launch(void* const* d_in, const int* in_sizes, int n_in,
                              void* d_out, int out_size, void* d_ws, size_t ws_size,
                              hipStream_t stream) {
  const float* hidden      = (const float*)d_in[0];
  const float* init_tensor = (const float*)d_in[1];
  const float* emb_table   = (const float*)d_in[2];
  const float* w_ih        = (const float*)d_in[3];
  const float* w_hh        = (const float*)d_in[4];
  const float* b_ih        = (const float*)d_in[5];
  const float* b_hh        = (const float*)d_in[6];
  const float* w_out       = (const float*)d_in[7];
  const float* b_out       = (const float*)d_in[8];
  const int*   seq_lens    = (const int*)d_in[9];
  float* out = (float*)d_out;
  float* ws  = (float*)d_ws;

  const size_t U_OFF   = 0;                                 // 2*4*1152*16 = 147456
  const size_t C_OFF   = U_OFF + (size_t)2 * 4 * KU_ * 16;
  const size_t LP_OFF  = C_OFF + (size_t)H_ * B_;           // +65536
  const size_t BAR_OFF = LP_OFF + (size_t)B_ * 64 * O_;     // +2097152
  const size_t PAMV_OFF= BAR_OFF + 64;
  const size_t PAMI_OFF= PAMV_OFF + 256;
  const size_t WC_OFF  = PAMI_OFF + 256;
  const size_t XW_OFF  = WC_OFF + (size_t)G4_ * KU_;        // +4718592 (~28.3 MB fixed)

  long long avail = (long long)(ws_size / 4) - (long long)XW_OFF;
  long long chl = avail / ((long long)B_ * G4_);
  int CH = (int)(chl < 1 ? 1 : (chl > S_ ? S_ : chl));

  unsigned* bar = (unsigned*)(ws + BAR_OFF);

  k_init<<<dim3(2048), dim3(256), 0, stream>>>(init_tensor, w_ih, w_hh,
                                               ws + U_OFF, ws + C_OFF,
                                               ws + WC_OFF, bar);

  unsigned bar_base = 0;
  for (int t0 = 0; t0 < S_; t0 += CH) {
    int ch = (S_ - t0 < CH) ? (S_ - t0) : CH;
    int rows = ch * B_;
    dim3 pg((rows + 127) / 128, G4_ / 128);
    k_xw<<<pg, dim3(256), 0, stream>>>(hidden, w_ih, b_ih, b_hh, ws + XW_OFF, t0, rows);

    const float* wcatp = ws + WC_OFF;
    const float* xwbp  = ws + XW_OFF;
    float* u_p  = ws + U_OFF;
    float* c_p  = ws + C_OFF;
    float* lp_p = ws + LP_OFF;
    float* pv_p = ws + PAMV_OFF;
    int*   pi_p = (int*)(ws + PAMI_OFF);
    int t0v = t0, nst = ch, upx = (t0 > 0) ? 1 : 0;
    void* args[] = { (void*)&wcatp, (void*)&w_out, (void*)&b_out,
                     (void*)&emb_table, (void*)&seq_lens, (void*)&xwbp,
                     (void*)&u_p, (void*)&c_p, (void*)&lp_p,
                     (void*)&pv_p, (void*)&pi_p, (void*)&out,
                     (void*)&bar, (void*)&bar_base, (void*)&t0v, (void*)&nst, (void*)&upx };
    hipLaunchCooperativeKernel((void*)k_steps, dim3(256), dim3(512), args, 0, stream);
    bar_base += (unsigned)(2 * ch) * 256u;
  }
}